// Round 13
// baseline (130.156 us; speedup 1.0000x reference)
//
#include <hip/hip_runtime.h>
#include <hip/hip_fp16.h>
#include <cstdint>
#include <cstddef>

#define DEV __device__ __forceinline__

namespace {

constexpr float SCALE  = 0.35355339059327373f;  // 8^-0.5
constexpr float RATIO  = 63.0f / 127.0f;        // grid->input scale
constexpr float RANGEF = 11.0f;
constexpr float EPS    = 1e-6f;

typedef _Float16 h2 __attribute__((ext_vector_type(2)));

DEV float fdot2(h2 a, h2 b, float c) { return __builtin_amdgcn_fdot2(a, b, c, false); }
DEV h2 pkrtz(float a, float b) {
  auto r = __builtin_amdgcn_cvt_pkrtz(a, b);
  union { decltype(r) i; h2 o; } u; u.i = r; return u.o;
}
DEV h2 permh(unsigned a, unsigned b, unsigned sel) {
  unsigned r = __builtin_amdgcn_perm(a, b, sel);
  union { unsigned u; h2 h; } u; u.u = r; return u.h;
}
DEV void fax(float4& a, float s, const float4& b) {
  a.x = fmaf(s, b.x, a.x); a.y = fmaf(s, b.y, a.y);
  a.z = fmaf(s, b.z, a.z); a.w = fmaf(s, b.w, a.w);
}

// corner weights/indices for one bilinear sample
DEV void corners(float iy, float ix, float* wc, int* idx) {
  float yf = floorf(iy), xf = floorf(ix);
  float wy = iy - yf, wx = ix - xf;
  int y0 = (int)yf, x0 = (int)xf;
  #pragma unroll
  for (int c = 0; c < 4; ++c) {
    int yy = y0 + (c >> 1), xx = x0 + (c & 1);
    bool valid = ((unsigned)yy < 64u) && ((unsigned)xx < 64u);
    float w = ((c >> 1) ? wy : 1.f - wy) * ((c & 1) ? wx : 1.f - wx);
    wc[c] = valid ? w : 0.f;
    idx[c] = valid ? yy * 64 + xx : 0;
  }
}

// ---- transpose x -> vH fp16 (B,4096,128), block 0 also repacks weights -----
__global__ __launch_bounds__(256) void k_transpose(
    const float* __restrict__ x, __half* __restrict__ vH,
    const float* __restrict__ offw, const float* __restrict__ dww,
    const float* __restrict__ wq, const float* __restrict__ wk,
    const float* __restrict__ rpb,
    float* __restrict__ wT2, float* __restrict__ dwT,
    float* __restrict__ wqT, float* __restrict__ wkT, h2* __restrict__ rpbH) {
  if (blockIdx.x == 0) {
    for (int idx = threadIdx.x; idx < 18 * 16 * 9; idx += 256) {
      int o = idx / 144, j = (idx / 9) % 16, tap = idx % 9;
      int h = o / 9, i = o % 9;
      wT2[((tap * 2 + h) * 16 + j) * 9 + i] = offw[idx];
    }
    for (int idx = threadIdx.x; idx < 144; idx += 256) {
      int j = idx / 9, tap = idx % 9;
      dwT[tap * 16 + j] = dww[idx];
    }
    for (int idx = threadIdx.x; idx < 4096; idx += 256) {
      int c = idx >> 5, o = idx & 31;
      wqT[c * 32 + o] = wq[o * 128 + c];
      wkT[c * 32 + o] = wk[o * 128 + c];
    }
    for (int idx = threadIdx.x; idx < 144; idx += 256) {
      int row = idx >> 2, j = idx & 3;
      rpbH[idx] = pkrtz(rpb[row * 8 + 2 * j], rpb[row * 8 + 2 * j + 1]);
    }
  }
  __shared__ float tile[128 * 65];
  int b = blockIdx.x >> 6, y = blockIdx.x & 63;
  const float* xp = x + (size_t)b * 128 * 4096 + (size_t)y * 64;
  int xc = threadIdx.x & 63, cb = threadIdx.x >> 6;
  #pragma unroll
  for (int i = 0; i < 32; ++i) {
    int c = cb * 32 + i;
    tile[c * 65 + xc] = xp[(size_t)c * 4096 + xc];
  }
  __syncthreads();
  int p = threadIdx.x >> 2, c0 = (threadIdx.x & 3) * 32;
  __half* op = vH + ((size_t)b * 4096 + (size_t)y * 64 + p) * 128 + c0;
  #pragma unroll
  for (int i = 0; i < 32; i += 8) {
    union { float4 f; __half2 h[4]; } u;
    #pragma unroll
    for (int j = 0; j < 4; ++j)
      u.h[j] = __floats2half2_rn(tile[(c0 + i + 2 * j) * 65 + p],
                                 tile[(c0 + i + 2 * j + 1) * 65 + p]);
    *(float4*)(op + i) = u.f;
  }
}

// ---- channel-LN + q/k projection: thread = (pos, 4 outputs) ----------------
__global__ __launch_bounds__(256) void k_lnproj(
    const float* __restrict__ x, const float* __restrict__ lnw,
    const float* __restrict__ lnb, const float* __restrict__ wqT,
    const float* __restrict__ wkT, float* __restrict__ qT,
    __half* __restrict__ kH) {
  int tid = blockIdx.x * 256 + threadIdx.x;  // [0, B*4096*16)
  int pos = tid >> 4, o4 = tid & 15;         // o4 0-7: q, 8-15: k
  int b = pos >> 12, sp = pos & 4095;
  const float* xp = x + (size_t)b * 524288 + sp;

  float s = 0.f, ss = 0.f;
  #pragma unroll
  for (int i = 0; i < 8; ++i) {
    float v = xp[(size_t)(o4 * 8 + i) * 4096];
    s += v; ss = fmaf(v, v, ss);
  }
  #pragma unroll
  for (int m = 1; m < 16; m <<= 1) {
    s += __shfl_xor(s, m);
    ss += __shfl_xor(ss, m);
  }
  float mean = s * (1.f / 128.f);
  float rstd = rsqrtf(ss * (1.f / 128.f) - mean * mean + EPS);

  int isk = o4 >> 3;
  const float* w = (isk ? wkT : wqT) + (o4 & 7) * 4;
  float a0 = 0.f, a1 = 0.f, a2 = 0.f, a3 = 0.f;
  #pragma unroll 4
  for (int c = 0; c < 128; ++c) {
    float xn = (xp[(size_t)c * 4096] - mean) * rstd * lnw[c] + lnb[c];
    const float* wr = w + c * 32;
    a0 = fmaf(wr[0], xn, a0); a1 = fmaf(wr[1], xn, a1);
    a2 = fmaf(wr[2], xn, a2); a3 = fmaf(wr[3], xn, a3);
  }
  if (!isk) {
    *(float4*)(qT + (size_t)pos * 32 + (o4 & 7) * 4) = make_float4(a0, a1, a2, a3);
  } else {
    union { uint2 u; __half2 h[2]; } o;
    o.h[0] = __floats2half2_rn(a0, a1);
    o.h[1] = __floats2half2_rn(a2, a3);
    *(uint2*)(kH + (size_t)pos * 32 + (o4 & 7) * 4) = o.u;
  }
}

// ---- bilinear 64->128 resize: thread = (pos, 8ch) --------------------------
__global__ __launch_bounds__(256) void k_resize(const float* __restrict__ qT,
                                                float* __restrict__ qrT) {
  int tid = blockIdx.x * 256 + threadIdx.x;  // [0, np*4)
  int pos = tid >> 2, q4 = tid & 3;
  int b = pos >> 14, rem = pos & 16383;
  int oy = rem >> 7, ox = rem & 127;
  float ys = oy * RATIO, xs = ox * RATIO;
  float yf = floorf(ys), xf = floorf(xs);
  int y0 = (int)yf, x0 = (int)xf;
  int y1 = min(y0 + 1, 63), x1 = min(x0 + 1, 63);
  float wy = ys - yf, wx = xs - xf;
  const float4* p00 = (const float4*)(qT + ((size_t)b * 4096 + y0 * 64 + x0) * 32 + q4 * 8);
  const float4* p01 = (const float4*)(qT + ((size_t)b * 4096 + y0 * 64 + x1) * 32 + q4 * 8);
  const float4* p10 = (const float4*)(qT + ((size_t)b * 4096 + y1 * 64 + x0) * 32 + q4 * 8);
  const float4* p11 = (const float4*)(qT + ((size_t)b * 4096 + y1 * 64 + x1) * 32 + q4 * 8);
  float w00 = (1.f - wy) * (1.f - wx), w01 = (1.f - wy) * wx;
  float w10 = wy * (1.f - wx), w11 = wy * wx;
  float4* op = (float4*)(qrT + (size_t)pos * 32 + q4 * 8);
  #pragma unroll
  for (int i = 0; i < 2; ++i) {
    float4 r = {0.f, 0.f, 0.f, 0.f};
    fax(r, w00, p00[i]); fax(r, w01, p01[i]);
    fax(r, w10, p10[i]); fax(r, w11, p11[i]);
    op[i] = r;
  }
}

// ---- depthwise 3x3 + group-LN + SiLU: thread = (pos, 8ch) ------------------
__global__ __launch_bounds__(256) void k_dwln(
    const float* __restrict__ qrT, const float* __restrict__ dwT,
    const float* __restrict__ olnw, const float* __restrict__ olnb,
    float* __restrict__ tT) {
  int tid = blockIdx.x * 256 + threadIdx.x;  // [0, np*4)
  int pos = tid >> 2, sub = tid & 3;         // sub = g*2 + h8
  int b = pos >> 14, rem = pos & 16383;
  int oy = rem >> 7, ox = rem & 127;
  int h8 = sub & 1;
  float4 a0 = {}, a1 = {};
  #pragma unroll
  for (int kh = 0; kh < 3; ++kh) {
    int ty = oy + kh - 1;
    if ((unsigned)ty >= 128u) continue;
    #pragma unroll
    for (int kw = 0; kw < 3; ++kw) {
      int tx = ox + kw - 1;
      if ((unsigned)tx >= 128u) continue;
      int tap = kh * 3 + kw;
      const float4* p =
          (const float4*)(qrT + ((size_t)b * 16384 + (size_t)ty * 128 + tx) * 32 + sub * 8);
      const float* dw = dwT + tap * 16 + h8 * 8;
      float4 v0 = p[0], v1 = p[1];
      a0.x = fmaf(dw[0], v0.x, a0.x); a0.y = fmaf(dw[1], v0.y, a0.y);
      a0.z = fmaf(dw[2], v0.z, a0.z); a0.w = fmaf(dw[3], v0.w, a0.w);
      a1.x = fmaf(dw[4], v1.x, a1.x); a1.y = fmaf(dw[5], v1.y, a1.y);
      a1.z = fmaf(dw[6], v1.z, a1.z); a1.w = fmaf(dw[7], v1.w, a1.w);
    }
  }
  float s = a0.x + a0.y + a0.z + a0.w + a1.x + a1.y + a1.z + a1.w;
  float ss = a0.x * a0.x + a0.y * a0.y + a0.z * a0.z + a0.w * a0.w +
             a1.x * a1.x + a1.y * a1.y + a1.z * a1.z + a1.w * a1.w;
  s += __shfl_xor(s, 1);
  ss += __shfl_xor(ss, 1);
  float mean = s * (1.f / 16.f);
  float rstd = rsqrtf(ss * (1.f / 16.f) - mean * mean + EPS);
  const float* ow = olnw + h8 * 8;
  const float* ob = olnb + h8 * 8;
  float r[8] = {a0.x, a0.y, a0.z, a0.w, a1.x, a1.y, a1.z, a1.w};
  #pragma unroll
  for (int i = 0; i < 8; ++i) {
    float t = (r[i] - mean) * rstd * ow[i] + ob[i];
    r[i] = t / (1.f + expf(-t));
  }
  float4* op = (float4*)(tT + (size_t)pos * 32 + sub * 8);
  op[0] = make_float4(r[0], r[1], r[2], r[3]);
  op[1] = make_float4(r[4], r[5], r[6], r[7]);
}

// ---- 16->18 3x3 conv + tanh*RANGE + abs coords: tT -> crd ------------------
__global__ __launch_bounds__(256) void k_off(
    const float* __restrict__ tT, const float* __restrict__ wT2,
    const float* __restrict__ offb, float* __restrict__ crd) {
  int tid = blockIdx.x * 128 + (threadIdx.x & 127);  // [0, B*2*16384)
  int h = __builtin_amdgcn_readfirstlane(threadIdx.x >> 7);
  int bg = tid >> 14, rem = tid & 16383;
  int oy = rem >> 7, ox = rem & 127;
  int b = bg >> 1, g = bg & 1;

  float a[9];
  #pragma unroll
  for (int i = 0; i < 9; ++i) a[i] = 0.f;

  #pragma unroll
  for (int kh = 0; kh < 3; ++kh) {
    int ty = oy + kh - 1;
    if (ty < 0 || ty >= 128) continue;
    const float* base = tT + ((size_t)b * 16384 + (size_t)ty * 128) * 32 + g * 16;
    #pragma unroll
    for (int kw = 0; kw < 3; ++kw) {
      int tap = kh * 3 + kw;
      int tx = ox + kw - 1;
      if ((unsigned)tx >= 128u) continue;
      const float4* p = (const float4*)(base + (size_t)tx * 32);
      float4 A0 = p[0], A1 = p[1], A2 = p[2], A3 = p[3];
      float in[16] = {A0.x, A0.y, A0.z, A0.w, A1.x, A1.y, A1.z, A1.w,
                      A2.x, A2.y, A2.z, A2.w, A3.x, A3.y, A3.z, A3.w};
      const float* wrow = wT2 + (size_t)(tap * 2 + h) * 144;
      #pragma unroll
      for (int j = 0; j < 16; ++j) {
        float f = in[j];
        #pragma unroll
        for (int i = 0; i < 9; ++i)
          a[i] = fmaf(wrow[j * 9 + i], f, a[i]);
      }
    }
  }

  const float* bb = offb + h * 9;
  float* cp = crd + (size_t)tid * 18 + h * 9;
  #pragma unroll
  for (int i = 0; i < 9; ++i) {
    int o = h * 9 + i;
    int kp = o >> 1;
    float basec = (o & 1) ? (float)(kp % 3 - 1 + ox) : (float)(kp / 3 - 1 + oy);
    cp[i] = fmaf(tanhf(a[i] + bb[i]), RANGEF, basec) * RATIO;
  }
}

// ---- FUSED attention v5: exact-256 phase B, kp8 in barrier-free A2 ---------
__global__ __launch_bounds__(256) void k_attn2(
    const float* __restrict__ qrT, const __half* __restrict__ kH,
    const __half* __restrict__ vH, const float* __restrict__ crd,
    const h2* __restrict__ rpbH, float* __restrict__ out) {
  __shared__ h2 qh2S[256];                         // 16 pos x 16 half2
  __shared__ float crdS[576];                      // [g][pos][18]
  __shared__ __align__(16) float4 corn4[576];      // [pos][g][kp][2]
  __shared__ float lgS[576];
  int b = blockIdx.x >> 10;
  int p0 = (blockIdx.x & 1023) * 16;
  const h2* kbase = (const h2*)(kH + (size_t)b * 131072);

  // phase A: stage scaled q (fp16) + crd
  {
    int pp = threadIdx.x >> 4, j = threadIdx.x & 15;
    float2 qv = *(const float2*)(qrT + ((size_t)b * 16384 + p0 + pp) * 32 + j * 2);
    qh2S[threadIdx.x] = pkrtz(qv.x * SCALE, qv.y * SCALE);
    if (threadIdx.x < 144) {
      int g = threadIdx.x / 72, i = threadIdx.x - (threadIdx.x / 72) * 72;
      const float4* src = (const float4*)(crd + ((size_t)(b * 2 + g) * 16384 + p0) * 18);
      *(float4*)(crdS + g * 288 + i * 4) = src[i];
    }
  }

  // phase A2 (threads 0..31, barrier-free): kp=8 task per (pos, g).
  // Reads crd + q straight from global; writes lgS/corn4 before the barrier.
  if (threadIdx.x < 32) {
    int pl = threadIdx.x >> 1, g = threadIdx.x & 1;
    float2 cc = *(const float2*)(crd +
        ((size_t)(b * 2 + g) * 16384 + p0 + pl) * 18 + 16);
    float wc[4]; int idx[4];
    corners(cc.x, cc.y, wc, idx);

    h2 qa[8];
    const float* qg = qrT + ((size_t)b * 16384 + p0 + pl) * 32 + g * 16;
    #pragma unroll
    for (int j = 0; j < 8; ++j) {
      float2 qv = *(const float2*)(qg + 2 * j);
      qa[j] = pkrtz(qv.x * SCALE, qv.y * SCALE);
    }
    const h2* kb = kbase + g * 8;
    float a0 = 0.f, a1 = 0.f;
    #pragma unroll
    for (int c = 0; c < 4; ++c) {
      union { float4 f[2]; h2 h[8]; } kk;
      const float4* kr = (const float4*)(kb + (size_t)idx[c] * 16);
      kk.f[0] = kr[0]; kk.f[1] = kr[1];
      float d0 = 0.f, d1 = 0.f;
      #pragma unroll
      for (int j = 0; j < 4; ++j) {
        d0 = fdot2(qa[j], kk.h[j], d0);
        d1 = fdot2(qa[4 + j], kk.h[4 + j], d1);
      }
      a0 = fmaf(wc[c], d0, a0);
      a1 = fmaf(wc[c], d1, a1);
    }
    const h2* rp0 = rpbH + (2 * g * 9 + 8) * 4;
    const h2* rp1 = rpbH + ((2 * g + 1) * 9 + 8) * 4;
    #pragma unroll
    for (int j = 0; j < 4; ++j) {
      a0 = fdot2(qa[j], rp0[j], a0);
      a1 = fdot2(qa[4 + j], rp1[j], a1);
    }
    lgS[(pl * 4 + 2 * g) * 9 + 8] = a0;
    lgS[(pl * 4 + 2 * g + 1) * 9 + 8] = a1;
    corn4[((pl * 2 + g) * 9 + 8) * 2 + 0] =
        make_float4(wc[0], __int_as_float(idx[0]), wc[1], __int_as_float(idx[1]));
    corn4[((pl * 2 + g) * 9 + 8) * 2 + 1] =
        make_float4(wc[2], __int_as_float(idx[2]), wc[3], __int_as_float(idx[3]));
  }
  __syncthreads();

  // phase B: exactly 256 tasks = (pos, g, kp 0..7)
  {
    int pl = threadIdx.x >> 4, r = threadIdx.x & 15;
    int g = r >> 3, kp = r & 7;
    float iy = crdS[g * 288 + pl * 18 + 2 * kp];
    float ix = crdS[g * 288 + pl * 18 + 2 * kp + 1];
    float wc[4]; int idx[4];
    corners(iy, ix, wc, idx);

    const h2* qa = qh2S + pl * 16 + g * 8;
    const h2* kb = kbase + g * 8;
    float a0 = 0.f, a1 = 0.f;
    #pragma unroll
    for (int c = 0; c < 4; ++c) {
      union { float4 f[2]; h2 h[8]; } kk;
      const float4* kr = (const float4*)(kb + (size_t)idx[c] * 16);
      kk.f[0] = kr[0]; kk.f[1] = kr[1];
      float d0 = 0.f, d1 = 0.f;
      #pragma unroll
      for (int j = 0; j < 4; ++j) {
        d0 = fdot2(qa[j], kk.h[j], d0);
        d1 = fdot2(qa[4 + j], kk.h[4 + j], d1);
      }
      a0 = fmaf(wc[c], d0, a0);
      a1 = fmaf(wc[c], d1, a1);
    }
    const h2* rp0 = rpbH + (2 * g * 9 + kp) * 4;
    const h2* rp1 = rpbH + ((2 * g + 1) * 9 + kp) * 4;
    #pragma unroll
    for (int j = 0; j < 4; ++j) {
      a0 = fdot2(qa[j], rp0[j], a0);
      a1 = fdot2(qa[4 + j], rp1[j], a1);
    }
    lgS[(pl * 4 + 2 * g) * 9 + kp] = a0;
    lgS[(pl * 4 + 2 * g + 1) * 9 + kp] = a1;
    corn4[((pl * 2 + g) * 9 + kp) * 2 + 0] =
        make_float4(wc[0], __int_as_float(idx[0]), wc[1], __int_as_float(idx[1]));
    corn4[((pl * 2 + g) * 9 + kp) * 2 + 1] =
        make_float4(wc[2], __int_as_float(idx[2]), wc[3], __int_as_float(idx[3]));
  }
  __syncthreads();

  // phase D: per-thread softmax + plain v-gather loop
  int pl = threadIdx.x >> 4, c8 = threadIdx.x & 15;
  int g = c8 >> 3, h = c8 >> 2, ch = c8 * 8;
  int pos = p0 + pl;

  float w9[9];
  {
    const float* l = lgS + (pl * 4 + h) * 9;
    float m = l[0];
    #pragma unroll
    for (int kp = 1; kp < 9; ++kp) m = fmaxf(m, l[kp]);
    float s = 0.f;
    #pragma unroll
    for (int kp = 0; kp < 9; ++kp) { w9[kp] = __expf(l[kp] - m); s += w9[kp]; }
    float inv = 1.f / s;
    #pragma unroll
    for (int kp = 0; kp < 9; ++kp) w9[kp] *= inv;
  }

  const __half* vb = vH + (size_t)b * 524288 + ch;
  const float4* corn = corn4 + (pl * 2 + g) * 18;
  constexpr unsigned SEL_LO = 0x01000504u, SEL_HI = 0x03020706u;

  float acc[8] = {};
  #pragma unroll
  for (int kp = 0; kp < 9; ++kp) {
    float aw = w9[kp];
    float4 ca = corn[kp * 2], cb = corn[kp * 2 + 1];
    #pragma unroll
    for (int pr = 0; pr < 2; ++pr) {
      float4 cp = pr ? cb : ca;
      h2 w01 = pkrtz(aw * cp.x, aw * cp.z);
      uint4 r0 = *(const uint4*)(vb + (size_t)__float_as_int(cp.y) * 128);
      uint4 r1 = *(const uint4*)(vb + (size_t)__float_as_int(cp.w) * 128);
      acc[0] = fdot2(w01, permh(r0.x, r1.x, SEL_LO), acc[0]);
      acc[1] = fdot2(w01, permh(r0.x, r1.x, SEL_HI), acc[1]);
      acc[2] = fdot2(w01, permh(r0.y, r1.y, SEL_LO), acc[2]);
      acc[3] = fdot2(w01, permh(r0.y, r1.y, SEL_HI), acc[3]);
      acc[4] = fdot2(w01, permh(r0.z, r1.z, SEL_LO), acc[4]);
      acc[5] = fdot2(w01, permh(r0.z, r1.z, SEL_HI), acc[5]);
      acc[6] = fdot2(w01, permh(r0.w, r1.w, SEL_LO), acc[6]);
      acc[7] = fdot2(w01, permh(r0.w, r1.w, SEL_HI), acc[7]);
    }
  }

  float* op = out + ((size_t)b * 128 + ch) * 16384 + pos;
  #pragma unroll
  for (int i = 0; i < 8; ++i) op[(size_t)i * 16384] = acc[i];
}

}  // namespace

extern "C" void kernel_launch(void* const* d_in, const int* in_sizes, int n_in,
                              void* d_out, int out_size, void* d_ws, size_t ws_size,
                              hipStream_t stream) {
  const float* x    = (const float*)d_in[0];
  const float* lnw  = (const float*)d_in[1];
  const float* lnb  = (const float*)d_in[2];
  const float* wq   = (const float*)d_in[3];
  const float* wk   = (const float*)d_in[4];
  const float* dww  = (const float*)d_in[5];
  const float* olnw = (const float*)d_in[6];
  const float* olnb = (const float*)d_in[7];
  const float* offw = (const float*)d_in[8];
  const float* offb = (const float*)d_in[9];
  const float* rpb  = (const float*)d_in[10];
  float* outp = (float*)d_out;

  int B = in_sizes[0] / (128 * 64 * 64);
  size_t nb = (size_t)B * 4096;   // input positions
  size_t np = (size_t)B * 16384;  // output positions

  char* w8 = (char*)d_ws;
  __half* vH  = (__half*)w8;  w8 += nb * 128 * 2;
  __half* kH  = (__half*)w8;  w8 += nb * 32 * 2;
  float*  qT  = (float*)w8;   w8 += nb * 32 * 4;
  float*  qrT = (float*)w8;   w8 += np * 32 * 4;
  float*  tT  = (float*)w8;   w8 += np * 32 * 4;
  float*  crd = (float*)w8;   w8 += np * 2 * 18 * 4;
  float*  wT2 = (float*)w8;   w8 += 2592 * 4;
  float*  dwT = (float*)w8;   w8 += 144 * 4;
  float*  wqT = (float*)w8;   w8 += 4096 * 4;
  float*  wkT = (float*)w8;   w8 += 4096 * 4;
  h2*     rpbH= (h2*)w8;      w8 += 1024;

  hipLaunchKernelGGL(k_transpose, dim3(B * 64), dim3(256), 0, stream,
                     x, vH, offw, dww, wq, wk, rpb, wT2, dwT, wqT, wkT, rpbH);
  hipLaunchKernelGGL(k_lnproj, dim3(B * 256), dim3(256), 0, stream,
                     x, lnw, lnb, wqT, wkT, qT, kH);
  hipLaunchKernelGGL(k_resize, dim3(B * 256), dim3(256), 0, stream, qT, qrT);
  hipLaunchKernelGGL(k_dwln, dim3(B * 256), dim3(256), 0, stream,
                     qrT, dwT, olnw, olnb, tT);
  hipLaunchKernelGGL(k_off, dim3(B * 256), dim3(256), 0, stream, tT, wT2, offb, crd);
  hipLaunchKernelGGL(k_attn2, dim3(B * 1024), dim3(256), 0, stream,
                     qrT, kH, vH, crd, rpbH, outp);
}

// Round 14
// 107.849 us; speedup vs baseline: 1.2068x; 1.2068x over previous
//
#include <hip/hip_runtime.h>
#include <hip/hip_fp16.h>
#include <cstdint>
#include <cstddef>

#define DEV __device__ __forceinline__

namespace {

constexpr float SCALE  = 0.35355339059327373f;  // 8^-0.5
constexpr float RATIO  = 63.0f / 127.0f;        // grid->input scale
constexpr float RANGEF = 11.0f;
constexpr float EPS    = 1e-6f;

typedef _Float16 h2 __attribute__((ext_vector_type(2)));

DEV float fdot2(h2 a, h2 b, float c) { return __builtin_amdgcn_fdot2(a, b, c, false); }
DEV h2 pkrtz(float a, float b) {
  auto r = __builtin_amdgcn_cvt_pkrtz(a, b);
  union { decltype(r) i; h2 o; } u; u.i = r; return u.o;
}
DEV h2 permh(unsigned a, unsigned b, unsigned sel) {
  unsigned r = __builtin_amdgcn_perm(a, b, sel);
  union { unsigned u; h2 h; } u; u.u = r; return u.h;
}
DEV void fax(float4& a, float s, const float4& b) {
  a.x = fmaf(s, b.x, a.x); a.y = fmaf(s, b.y, a.y);
  a.z = fmaf(s, b.z, a.z); a.w = fmaf(s, b.w, a.w);
}

// corner weights/indices for one bilinear sample
DEV void corners(float iy, float ix, float* wc, int* idx) {
  float yf = floorf(iy), xf = floorf(ix);
  float wy = iy - yf, wx = ix - xf;
  int y0 = (int)yf, x0 = (int)xf;
  #pragma unroll
  for (int c = 0; c < 4; ++c) {
    int yy = y0 + (c >> 1), xx = x0 + (c & 1);
    bool valid = ((unsigned)yy < 64u) && ((unsigned)xx < 64u);
    float w = ((c >> 1) ? wy : 1.f - wy) * ((c & 1) ? wx : 1.f - wx);
    wc[c] = valid ? w : 0.f;
    idx[c] = valid ? yy * 64 + xx : 0;
  }
}

// ---- transpose x -> vH fp16 (B,4096,128), block 0 also repacks weights -----
__global__ __launch_bounds__(256) void k_transpose(
    const float* __restrict__ x, __half* __restrict__ vH,
    const float* __restrict__ offw, const float* __restrict__ dww,
    const float* __restrict__ wq, const float* __restrict__ wk,
    const float* __restrict__ rpb,
    h2* __restrict__ wT2H, float* __restrict__ dwT,
    h2* __restrict__ wqH, h2* __restrict__ wkH, h2* __restrict__ rpbH) {
  if (blockIdx.x == 0) {
    // wT2H[((tap*2+h)*8 + j2)*9 + i] = h2(offw[(h*9+i)][2j2][tap], ..[2j2+1][tap])
    for (int idx = threadIdx.x; idx < 1296; idx += 256) {
      int t2 = idx / 72, r = idx % 72, j2 = r / 9, i = r % 9;
      int tap = t2 >> 1, h = t2 & 1;
      int o = h * 9 + i;
      wT2H[idx] = pkrtz(offw[o * 144 + (2 * j2) * 9 + tap],
                        offw[o * 144 + (2 * j2 + 1) * 9 + tap]);
    }
    for (int idx = threadIdx.x; idx < 144; idx += 256) {
      int j = idx / 9, tap = idx % 9;
      dwT[tap * 16 + j] = dww[idx];
    }
    // wqH[c2*32+o] = h2(wq[o][2c2], wq[o][2c2+1])
    for (int idx = threadIdx.x; idx < 2048; idx += 256) {
      int c2 = idx >> 5, o = idx & 31;
      wqH[idx] = pkrtz(wq[o * 128 + 2 * c2], wq[o * 128 + 2 * c2 + 1]);
      wkH[idx] = pkrtz(wk[o * 128 + 2 * c2], wk[o * 128 + 2 * c2 + 1]);
    }
    for (int idx = threadIdx.x; idx < 144; idx += 256) {
      int row = idx >> 2, j = idx & 3;
      rpbH[idx] = pkrtz(rpb[row * 8 + 2 * j], rpb[row * 8 + 2 * j + 1]);
    }
  }
  __shared__ float tile[128 * 65];
  int b = blockIdx.x >> 6, y = blockIdx.x & 63;
  const float* xp = x + (size_t)b * 128 * 4096 + (size_t)y * 64;
  int xc = threadIdx.x & 63, cb = threadIdx.x >> 6;
  #pragma unroll
  for (int i = 0; i < 32; ++i) {
    int c = cb * 32 + i;
    tile[c * 65 + xc] = xp[(size_t)c * 4096 + xc];
  }
  __syncthreads();
  int p = threadIdx.x >> 2, c0 = (threadIdx.x & 3) * 32;
  __half* op = vH + ((size_t)b * 4096 + (size_t)y * 64 + p) * 128 + c0;
  #pragma unroll
  for (int i = 0; i < 32; i += 8) {
    union { float4 f; __half2 h[4]; } u;
    #pragma unroll
    for (int j = 0; j < 4; ++j)
      u.h[j] = __floats2half2_rn(tile[(c0 + i + 2 * j) * 65 + p],
                                 tile[(c0 + i + 2 * j + 1) * 65 + p]);
    *(float4*)(op + i) = u.f;
  }
}

// ---- channel-LN + q/k projection (fp16 weights, fdot2) ---------------------
__global__ __launch_bounds__(256) void k_lnproj(
    const float* __restrict__ x, const float* __restrict__ lnw,
    const float* __restrict__ lnb, const h2* __restrict__ wqH,
    const h2* __restrict__ wkH, float* __restrict__ qT,
    __half* __restrict__ kH) {
  int tid = blockIdx.x * 256 + threadIdx.x;  // [0, B*4096*16)
  int pos = tid >> 4, o4 = tid & 15;         // o4 0-7: q, 8-15: k
  int b = pos >> 12, sp = pos & 4095;
  const float* xp = x + (size_t)b * 524288 + sp;

  float s = 0.f, ss = 0.f;
  #pragma unroll
  for (int i = 0; i < 8; ++i) {
    float v = xp[(size_t)(o4 * 8 + i) * 4096];
    s += v; ss = fmaf(v, v, ss);
  }
  #pragma unroll
  for (int m = 1; m < 16; m <<= 1) {
    s += __shfl_xor(s, m);
    ss += __shfl_xor(ss, m);
  }
  float mean = s * (1.f / 128.f);
  float rstd = rsqrtf(ss * (1.f / 128.f) - mean * mean + EPS);

  int isk = o4 >> 3;
  const h2* w = (isk ? wkH : wqH) + (o4 & 7) * 4;
  float a0 = 0.f, a1 = 0.f, a2 = 0.f, a3 = 0.f;
  #pragma unroll 4
  for (int c2 = 0; c2 < 64; ++c2) {
    float v0 = xp[(size_t)(2 * c2) * 4096];
    float v1 = xp[(size_t)(2 * c2 + 1) * 4096];
    float xn0 = (v0 - mean) * rstd * lnw[2 * c2] + lnb[2 * c2];
    float xn1 = (v1 - mean) * rstd * lnw[2 * c2 + 1] + lnb[2 * c2 + 1];
    h2 xh = pkrtz(xn0, xn1);
    const h2* wr = w + c2 * 32;
    a0 = fdot2(xh, wr[0], a0); a1 = fdot2(xh, wr[1], a1);
    a2 = fdot2(xh, wr[2], a2); a3 = fdot2(xh, wr[3], a3);
  }
  if (!isk) {
    *(float4*)(qT + (size_t)pos * 32 + (o4 & 7) * 4) = make_float4(a0, a1, a2, a3);
  } else {
    union { uint2 u; __half2 h[2]; } o;
    o.h[0] = __floats2half2_rn(a0, a1);
    o.h[1] = __floats2half2_rn(a2, a3);
    *(uint2*)(kH + (size_t)pos * 32 + (o4 & 7) * 4) = o.u;
  }
}

// ---- bilinear 64->128 resize: thread = (pos, 8ch) --------------------------
__global__ __launch_bounds__(256) void k_resize(const float* __restrict__ qT,
                                                float* __restrict__ qrT) {
  int tid = blockIdx.x * 256 + threadIdx.x;  // [0, np*4)
  int pos = tid >> 2, q4 = tid & 3;
  int b = pos >> 14, rem = pos & 16383;
  int oy = rem >> 7, ox = rem & 127;
  float ys = oy * RATIO, xs = ox * RATIO;
  float yf = floorf(ys), xf = floorf(xs);
  int y0 = (int)yf, x0 = (int)xf;
  int y1 = min(y0 + 1, 63), x1 = min(x0 + 1, 63);
  float wy = ys - yf, wx = xs - xf;
  const float4* p00 = (const float4*)(qT + ((size_t)b * 4096 + y0 * 64 + x0) * 32 + q4 * 8);
  const float4* p01 = (const float4*)(qT + ((size_t)b * 4096 + y0 * 64 + x1) * 32 + q4 * 8);
  const float4* p10 = (const float4*)(qT + ((size_t)b * 4096 + y1 * 64 + x0) * 32 + q4 * 8);
  const float4* p11 = (const float4*)(qT + ((size_t)b * 4096 + y1 * 64 + x1) * 32 + q4 * 8);
  float w00 = (1.f - wy) * (1.f - wx), w01 = (1.f - wy) * wx;
  float w10 = wy * (1.f - wx), w11 = wy * wx;
  float4* op = (float4*)(qrT + (size_t)pos * 32 + q4 * 8);
  #pragma unroll
  for (int i = 0; i < 2; ++i) {
    float4 r = {0.f, 0.f, 0.f, 0.f};
    fax(r, w00, p00[i]); fax(r, w01, p01[i]);
    fax(r, w10, p10[i]); fax(r, w11, p11[i]);
    op[i] = r;
  }
}

// ---- depthwise 3x3 + group-LN + SiLU: thread = (pos, 8ch) -> tH fp16 -------
__global__ __launch_bounds__(256) void k_dwln(
    const float* __restrict__ qrT, const float* __restrict__ dwT,
    const float* __restrict__ olnw, const float* __restrict__ olnb,
    __half* __restrict__ tH) {
  int tid = blockIdx.x * 256 + threadIdx.x;  // [0, np*4)
  int pos = tid >> 2, sub = tid & 3;         // sub = g*2 + h8
  int b = pos >> 14, rem = pos & 16383;
  int oy = rem >> 7, ox = rem & 127;
  int h8 = sub & 1;
  float4 a0 = {}, a1 = {};
  #pragma unroll
  for (int kh = 0; kh < 3; ++kh) {
    int ty = oy + kh - 1;
    if ((unsigned)ty >= 128u) continue;
    #pragma unroll
    for (int kw = 0; kw < 3; ++kw) {
      int tx = ox + kw - 1;
      if ((unsigned)tx >= 128u) continue;
      int tap = kh * 3 + kw;
      const float4* p =
          (const float4*)(qrT + ((size_t)b * 16384 + (size_t)ty * 128 + tx) * 32 + sub * 8);
      const float* dw = dwT + tap * 16 + h8 * 8;
      float4 v0 = p[0], v1 = p[1];
      a0.x = fmaf(dw[0], v0.x, a0.x); a0.y = fmaf(dw[1], v0.y, a0.y);
      a0.z = fmaf(dw[2], v0.z, a0.z); a0.w = fmaf(dw[3], v0.w, a0.w);
      a1.x = fmaf(dw[4], v1.x, a1.x); a1.y = fmaf(dw[5], v1.y, a1.y);
      a1.z = fmaf(dw[6], v1.z, a1.z); a1.w = fmaf(dw[7], v1.w, a1.w);
    }
  }
  float s = a0.x + a0.y + a0.z + a0.w + a1.x + a1.y + a1.z + a1.w;
  float ss = a0.x * a0.x + a0.y * a0.y + a0.z * a0.z + a0.w * a0.w +
             a1.x * a1.x + a1.y * a1.y + a1.z * a1.z + a1.w * a1.w;
  s += __shfl_xor(s, 1);
  ss += __shfl_xor(ss, 1);
  float mean = s * (1.f / 16.f);
  float rstd = rsqrtf(ss * (1.f / 16.f) - mean * mean + EPS);
  const float* ow = olnw + h8 * 8;
  const float* ob = olnb + h8 * 8;
  float r[8] = {a0.x, a0.y, a0.z, a0.w, a1.x, a1.y, a1.z, a1.w};
  #pragma unroll
  for (int i = 0; i < 8; ++i) {
    float t = (r[i] - mean) * rstd * ow[i] + ob[i];
    r[i] = t / (1.f + expf(-t));
  }
  union { uint4 u; h2 h[4]; } o_;
  o_.h[0] = pkrtz(r[0], r[1]); o_.h[1] = pkrtz(r[2], r[3]);
  o_.h[2] = pkrtz(r[4], r[5]); o_.h[3] = pkrtz(r[6], r[7]);
  *(uint4*)(tH + (size_t)pos * 32 + sub * 8) = o_.u;
}

// ---- 16->18 3x3 conv (fp16 in/weights, fdot2) + tanh + abs coords ----------
__global__ __launch_bounds__(256) void k_off(
    const __half* __restrict__ tH, const h2* __restrict__ wT2H,
    const float* __restrict__ offb, float* __restrict__ crd) {
  int tid = blockIdx.x * 128 + (threadIdx.x & 127);  // [0, B*2*16384)
  int h = __builtin_amdgcn_readfirstlane(threadIdx.x >> 7);
  int bg = tid >> 14, rem = tid & 16383;
  int oy = rem >> 7, ox = rem & 127;
  int b = bg >> 1, g = bg & 1;

  float a[9];
  #pragma unroll
  for (int i = 0; i < 9; ++i) a[i] = 0.f;

  #pragma unroll
  for (int kh = 0; kh < 3; ++kh) {
    int ty = oy + kh - 1;
    if (ty < 0 || ty >= 128) continue;
    const __half* base = tH + ((size_t)b * 16384 + (size_t)ty * 128) * 32 + g * 16;
    #pragma unroll
    for (int kw = 0; kw < 3; ++kw) {
      int tap = kh * 3 + kw;
      int tx = ox + kw - 1;
      if ((unsigned)tx >= 128u) continue;
      union { uint4 u[2]; h2 hh[8]; } in;
      const uint4* p = (const uint4*)(base + (size_t)tx * 32);
      in.u[0] = p[0]; in.u[1] = p[1];
      const h2* wrow = wT2H + (size_t)(tap * 2 + h) * 72;
      #pragma unroll
      for (int j2 = 0; j2 < 8; ++j2) {
        h2 f = in.hh[j2];
        #pragma unroll
        for (int i = 0; i < 9; ++i)
          a[i] = fdot2(f, wrow[j2 * 9 + i], a[i]);
      }
    }
  }

  const float* bb = offb + h * 9;
  float* cp = crd + (size_t)tid * 18 + h * 9;
  #pragma unroll
  for (int i = 0; i < 9; ++i) {
    int o = h * 9 + i;
    int kp = o >> 1;
    float basec = (o & 1) ? (float)(kp % 3 - 1 + ox) : (float)(kp / 3 - 1 + oy);
    cp[i] = fmaf(tanhf(a[i] + bb[i]), RANGEF, basec) * RATIO;
  }
}

// ---- FUSED attention v5: exact-256 phase B, kp8 in barrier-free A2 ---------
__global__ __launch_bounds__(256) void k_attn2(
    const float* __restrict__ qrT, const __half* __restrict__ kH,
    const __half* __restrict__ vH, const float* __restrict__ crd,
    const h2* __restrict__ rpbH, float* __restrict__ out) {
  __shared__ h2 qh2S[256];                         // 16 pos x 16 half2
  __shared__ float crdS[576];                      // [g][pos][18]
  __shared__ __align__(16) float4 corn4[576];      // [pos][g][kp][2]
  __shared__ float lgS[576];
  int b = blockIdx.x >> 10;
  int p0 = (blockIdx.x & 1023) * 16;
  const h2* kbase = (const h2*)(kH + (size_t)b * 131072);

  // phase A: stage scaled q (fp16) + crd
  {
    int pp = threadIdx.x >> 4, j = threadIdx.x & 15;
    float2 qv = *(const float2*)(qrT + ((size_t)b * 16384 + p0 + pp) * 32 + j * 2);
    qh2S[threadIdx.x] = pkrtz(qv.x * SCALE, qv.y * SCALE);
    if (threadIdx.x < 144) {
      int g = threadIdx.x / 72, i = threadIdx.x - (threadIdx.x / 72) * 72;
      const float4* src = (const float4*)(crd + ((size_t)(b * 2 + g) * 16384 + p0) * 18);
      *(float4*)(crdS + g * 288 + i * 4) = src[i];
    }
  }

  // phase A2 (threads 0..31, barrier-free): kp=8 task per (pos, g).
  if (threadIdx.x < 32) {
    int pl = threadIdx.x >> 1, g = threadIdx.x & 1;
    float2 cc = *(const float2*)(crd +
        ((size_t)(b * 2 + g) * 16384 + p0 + pl) * 18 + 16);
    float wc[4]; int idx[4];
    corners(cc.x, cc.y, wc, idx);

    h2 qa[8];
    const float* qg = qrT + ((size_t)b * 16384 + p0 + pl) * 32 + g * 16;
    #pragma unroll
    for (int j = 0; j < 8; ++j) {
      float2 qv = *(const float2*)(qg + 2 * j);
      qa[j] = pkrtz(qv.x * SCALE, qv.y * SCALE);
    }
    const h2* kb = kbase + g * 8;
    float a0 = 0.f, a1 = 0.f;
    #pragma unroll
    for (int c = 0; c < 4; ++c) {
      union { float4 f[2]; h2 h[8]; } kk;
      const float4* kr = (const float4*)(kb + (size_t)idx[c] * 16);
      kk.f[0] = kr[0]; kk.f[1] = kr[1];
      float d0 = 0.f, d1 = 0.f;
      #pragma unroll
      for (int j = 0; j < 4; ++j) {
        d0 = fdot2(qa[j], kk.h[j], d0);
        d1 = fdot2(qa[4 + j], kk.h[4 + j], d1);
      }
      a0 = fmaf(wc[c], d0, a0);
      a1 = fmaf(wc[c], d1, a1);
    }
    const h2* rp0 = rpbH + (2 * g * 9 + 8) * 4;
    const h2* rp1 = rpbH + ((2 * g + 1) * 9 + 8) * 4;
    #pragma unroll
    for (int j = 0; j < 4; ++j) {
      a0 = fdot2(qa[j], rp0[j], a0);
      a1 = fdot2(qa[4 + j], rp1[j], a1);
    }
    lgS[(pl * 4 + 2 * g) * 9 + 8] = a0;
    lgS[(pl * 4 + 2 * g + 1) * 9 + 8] = a1;
    corn4[((pl * 2 + g) * 9 + 8) * 2 + 0] =
        make_float4(wc[0], __int_as_float(idx[0]), wc[1], __int_as_float(idx[1]));
    corn4[((pl * 2 + g) * 9 + 8) * 2 + 1] =
        make_float4(wc[2], __int_as_float(idx[2]), wc[3], __int_as_float(idx[3]));
  }
  __syncthreads();

  // phase B: exactly 256 tasks = (pos, g, kp 0..7)
  {
    int pl = threadIdx.x >> 4, r = threadIdx.x & 15;
    int g = r >> 3, kp = r & 7;
    float iy = crdS[g * 288 + pl * 18 + 2 * kp];
    float ix = crdS[g * 288 + pl * 18 + 2 * kp + 1];
    float wc[4]; int idx[4];
    corners(iy, ix, wc, idx);

    const h2* qa = qh2S + pl * 16 + g * 8;
    const h2* kb = kbase + g * 8;
    float a0 = 0.f, a1 = 0.f;
    #pragma unroll
    for (int c = 0; c < 4; ++c) {
      union { float4 f[2]; h2 h[8]; } kk;
      const float4* kr = (const float4*)(kb + (size_t)idx[c] * 16);
      kk.f[0] = kr[0]; kk.f[1] = kr[1];
      float d0 = 0.f, d1 = 0.f;
      #pragma unroll
      for (int j = 0; j < 4; ++j) {
        d0 = fdot2(qa[j], kk.h[j], d0);
        d1 = fdot2(qa[4 + j], kk.h[4 + j], d1);
      }
      a0 = fmaf(wc[c], d0, a0);
      a1 = fmaf(wc[c], d1, a1);
    }
    const h2* rp0 = rpbH + (2 * g * 9 + kp) * 4;
    const h2* rp1 = rpbH + ((2 * g + 1) * 9 + kp) * 4;
    #pragma unroll
    for (int j = 0; j < 4; ++j) {
      a0 = fdot2(qa[j], rp0[j], a0);
      a1 = fdot2(qa[4 + j], rp1[j], a1);
    }
    lgS[(pl * 4 + 2 * g) * 9 + kp] = a0;
    lgS[(pl * 4 + 2 * g + 1) * 9 + kp] = a1;
    corn4[((pl * 2 + g) * 9 + kp) * 2 + 0] =
        make_float4(wc[0], __int_as_float(idx[0]), wc[1], __int_as_float(idx[1]));
    corn4[((pl * 2 + g) * 9 + kp) * 2 + 1] =
        make_float4(wc[2], __int_as_float(idx[2]), wc[3], __int_as_float(idx[3]));
  }
  __syncthreads();

  // phase D: per-thread softmax + plain v-gather loop
  int pl = threadIdx.x >> 4, c8 = threadIdx.x & 15;
  int g = c8 >> 3, h = c8 >> 2, ch = c8 * 8;
  int pos = p0 + pl;

  float w9[9];
  {
    const float* l = lgS + (pl * 4 + h) * 9;
    float m = l[0];
    #pragma unroll
    for (int kp = 1; kp < 9; ++kp) m = fmaxf(m, l[kp]);
    float s = 0.f;
    #pragma unroll
    for (int kp = 0; kp < 9; ++kp) { w9[kp] = __expf(l[kp] - m); s += w9[kp]; }
    float inv = 1.f / s;
    #pragma unroll
    for (int kp = 0; kp < 9; ++kp) w9[kp] *= inv;
  }

  const __half* vb = vH + (size_t)b * 524288 + ch;
  const float4* corn = corn4 + (pl * 2 + g) * 18;
  constexpr unsigned SEL_LO = 0x01000504u, SEL_HI = 0x03020706u;

  float acc[8] = {};
  #pragma unroll
  for (int kp = 0; kp < 9; ++kp) {
    float aw = w9[kp];
    float4 ca = corn[kp * 2], cb = corn[kp * 2 + 1];
    #pragma unroll
    for (int pr = 0; pr < 2; ++pr) {
      float4 cp = pr ? cb : ca;
      h2 w01 = pkrtz(aw * cp.x, aw * cp.z);
      uint4 r0 = *(const uint4*)(vb + (size_t)__float_as_int(cp.y) * 128);
      uint4 r1 = *(const uint4*)(vb + (size_t)__float_as_int(cp.w) * 128);
      acc[0] = fdot2(w01, permh(r0.x, r1.x, SEL_LO), acc[0]);
      acc[1] = fdot2(w01, permh(r0.x, r1.x, SEL_HI), acc[1]);
      acc[2] = fdot2(w01, permh(r0.y, r1.y, SEL_LO), acc[2]);
      acc[3] = fdot2(w01, permh(r0.y, r1.y, SEL_HI), acc[3]);
      acc[4] = fdot2(w01, permh(r0.z, r1.z, SEL_LO), acc[4]);
      acc[5] = fdot2(w01, permh(r0.z, r1.z, SEL_HI), acc[5]);
      acc[6] = fdot2(w01, permh(r0.w, r1.w, SEL_LO), acc[6]);
      acc[7] = fdot2(w01, permh(r0.w, r1.w, SEL_HI), acc[7]);
    }
  }

  float* op = out + ((size_t)b * 128 + ch) * 16384 + pos;
  #pragma unroll
  for (int i = 0; i < 8; ++i) op[(size_t)i * 16384] = acc[i];
}

}  // namespace

extern "C" void kernel_launch(void* const* d_in, const int* in_sizes, int n_in,
                              void* d_out, int out_size, void* d_ws, size_t ws_size,
                              hipStream_t stream) {
  const float* x    = (const float*)d_in[0];
  const float* lnw  = (const float*)d_in[1];
  const float* lnb  = (const float*)d_in[2];
  const float* wq   = (const float*)d_in[3];
  const float* wk   = (const float*)d_in[4];
  const float* dww  = (const float*)d_in[5];
  const float* olnw = (const float*)d_in[6];
  const float* olnb = (const float*)d_in[7];
  const float* offw = (const float*)d_in[8];
  const float* offb = (const float*)d_in[9];
  const float* rpb  = (const float*)d_in[10];
  float* outp = (float*)d_out;

  int B = in_sizes[0] / (128 * 64 * 64);
  size_t nb = (size_t)B * 4096;   // input positions
  size_t np = (size_t)B * 16384;  // output positions

  char* w8 = (char*)d_ws;
  __half* vH  = (__half*)w8;  w8 += nb * 128 * 2;
  __half* kH  = (__half*)w8;  w8 += nb * 32 * 2;
  float*  qT  = (float*)w8;   w8 += nb * 32 * 4;
  float*  qrT = (float*)w8;   w8 += np * 32 * 4;
  __half* tH  = (__half*)w8;  w8 += np * 32 * 2;
  float*  crd = (float*)w8;   w8 += np * 2 * 18 * 4;
  float*  dwT = (float*)w8;   w8 += 144 * 4;
  h2*     wqH = (h2*)w8;      w8 += 2048 * 4;
  h2*     wkH = (h2*)w8;      w8 += 2048 * 4;
  h2*     wT2H= (h2*)w8;      w8 += 1296 * 4;
  h2*     rpbH= (h2*)w8;      w8 += 1024;

  hipLaunchKernelGGL(k_transpose, dim3(B * 64), dim3(256), 0, stream,
                     x, vH, offw, dww, wq, wk, rpb, wT2H, dwT, wqH, wkH, rpbH);
  hipLaunchKernelGGL(k_lnproj, dim3(B * 256), dim3(256), 0, stream,
                     x, lnw, lnb, wqH, wkH, qT, kH);
  hipLaunchKernelGGL(k_resize, dim3(B * 256), dim3(256), 0, stream, qT, qrT);
  hipLaunchKernelGGL(k_dwln, dim3(B * 256), dim3(256), 0, stream,
                     qrT, dwT, olnw, olnb, tH);
  hipLaunchKernelGGL(k_off, dim3(B * 256), dim3(256), 0, stream, tH, wT2H, offb, crd);
  hipLaunchKernelGGL(k_attn2, dim3(B * 1024), dim3(256), 0, stream,
                     qrT, kH, vH, crd, rpbH, outp);
}